// Round 5
// baseline (133.818 us; speedup 1.0000x reference)
//
#include <hip/hip_runtime.h>

#define HH 256
#define WW 256
#define NPIX (2 * HH * WW)   // 131072 (B=2)
#define NC 48
#define NB 31
#define NG 6          // channel groups
#define CG 8          // channels per group (NG*CG == NC)
#define OT 32         // output tile (32x32 per block)
#define PT 38         // phi tile = OT+6
#define PSTR 44       // phi LDS row stride (16B aligned)
#define UT 44         // u tile = OT+12
#define USTR 52       // u LDS row stride (16B aligned)
#define TM 385        // phi-table points per channel, x in [-1.5,1.5], h=3/384

__device__ __forceinline__ float lerp_tab(const float* __restrict__ t, float x) {
    float s = fminf(fmaxf(fmaf(x, 128.f, 192.f), 0.f), 383.999f);
    float fj = floorf(s);
    int i = (int)fj;
    return fmaf(s - fj, t[i + 1] - t[i], t[i]);
}

// Fused: per-block phi tables -> conv1(7x7, 4ch/pass) -> table-lerp RBF ->
// conv2(flipped 7x7, 4ch/pass). All f32. Weights via block-uniform s_load.
// All per-lane accumulators are NAMED SCALARS (round 3: arrays -> scratch
// spill -> 700 MB HBM traffic). 4ch/pass halves conv1 LDS reads vs 2ch.
__global__ __launch_bounds__(256, 3)
void tnrd_main(const float* __restrict__ u,
               const float* __restrict__ wf,   // filters [48][49]
               const float* __restrict__ wr,   // rbf weights [48][31]
               float* __restrict__ part)
{
    __shared__ __align__(16) float u_s[UT * USTR];          //  9152 B
    __shared__ __align__(16) float phi_s[4][PT * PSTR];     // 26752 B
    __shared__ __align__(16) float tabs[CG][TM + 1];        // 12352 B

    const int tid = threadIdx.x;
    const int bx = blockIdx.x, by = blockIdx.y;
    const int b = blockIdx.z / NG, g = blockIdx.z % NG;
    const int c0 = g * CG;

    // ---- stage u tile (6-halo, zero-padded incl. stride pad) ----
    const int uy0 = by * OT - 6, ux0 = bx * OT - 6;
    const float* ub = u + b * (HH * WW);
    for (int i = tid; i < UT * USTR; i += 256) {
        int r = i / USTR, c = i - r * USTR;
        int gy = uy0 + r, gx = ux0 + c;
        float v = 0.f;
        if (c < UT && (unsigned)gy < HH && (unsigned)gx < WW)
            v = ub[gy * WW + gx];
        u_s[i] = v;
    }

    // ---- build this group's 8 phi tables in LDS (386 pts incl. lerp guard) ----
    #pragma unroll
    for (int ch = 0; ch < CG; ++ch) {
        const float* rc = wr + (c0 + ch) * NB;   // block-uniform -> s_load
        for (int j = tid; j < TM + 1; j += 256) {
            float x = fmaf((float)j, 3.0f / 384.0f, -1.5f);
            float s = 0.f;
            #pragma unroll
            for (int k = 0; k < NB; ++k) {
                float mu = -1.f + (float)k * (1.f / 15.f);
                float d = x - mu;
                s = fmaf(rc[k], __expf(-50.f * d * d), s);
            }
            tabs[ch][j] = s;
        }
    }
    __syncthreads();

    const int oy = tid >> 3;        // 0..31
    const int ox0 = (tid & 7) * 4;  // 0..28
    float o0 = 0.f, o1 = 0.f, o2 = 0.f, o3 = 0.f;
    const int py0 = by * OT - 3, px0 = bx * OT - 3;

    for (int pass = 0; pass < 2; ++pass) {       // 4 channels per pass
        const int ca = c0 + 4 * pass;
        const float* wA = wf + ca * 49;          // block-uniform -> s_load
        const float* wB = wA + 49;
        const float* wC = wB + 49;
        const float* wD = wC + 49;

        // ---- conv1 + RBF lerp, 4 channels; 380 items = 38 rows x 10 quads ----
        for (int p = 0; p < 2; ++p) {
            const int gi = tid + p * 256;
            if (gi < PT * 10) {
                const int pr = gi / 10, pc = (gi - pr * 10) * 4;
                float a0 = 0.f, a1 = 0.f, a2 = 0.f, a3 = 0.f;
                float b0 = 0.f, b1 = 0.f, b2 = 0.f, b3 = 0.f;
                float e0 = 0.f, e1 = 0.f, e2 = 0.f, e3 = 0.f;
                float d0 = 0.f, d1 = 0.f, d2 = 0.f, d3 = 0.f;
                const float* base = &u_s[pr * USTR + pc];
                #pragma unroll
                for (int dy = 0; dy < 7; ++dy) {
                    const float* row = base + dy * USTR;
                    float sv[12];
                    #pragma unroll
                    for (int j = 0; j < 12; ++j) sv[j] = row[j]; // 3x ds_read_b128
                    #pragma unroll
                    for (int dx = 0; dx < 7; ++dx) {
                        const float fa = wA[dy * 7 + dx];
                        const float fb = wB[dy * 7 + dx];
                        const float fc = wC[dy * 7 + dx];
                        const float fd = wD[dy * 7 + dx];
                        a0 = fmaf(sv[dx],     fa, a0);
                        a1 = fmaf(sv[dx + 1], fa, a1);
                        a2 = fmaf(sv[dx + 2], fa, a2);
                        a3 = fmaf(sv[dx + 3], fa, a3);
                        b0 = fmaf(sv[dx],     fb, b0);
                        b1 = fmaf(sv[dx + 1], fb, b1);
                        b2 = fmaf(sv[dx + 2], fb, b2);
                        b3 = fmaf(sv[dx + 3], fb, b3);
                        e0 = fmaf(sv[dx],     fc, e0);
                        e1 = fmaf(sv[dx + 1], fc, e1);
                        e2 = fmaf(sv[dx + 2], fc, e2);
                        e3 = fmaf(sv[dx + 3], fc, e3);
                        d0 = fmaf(sv[dx],     fd, d0);
                        d1 = fmaf(sv[dx + 1], fd, d1);
                        d2 = fmaf(sv[dx + 2], fd, d2);
                        d3 = fmaf(sv[dx + 3], fd, d3);
                    }
                }
                // ---- table lerp; phi = 0 outside image (conv2 zero-pad) ----
                const int gy = py0 + pr;
                const bool rowok = (unsigned)gy < HH;
                const bool k0 = rowok && (unsigned)(px0 + pc + 0) < WW;
                const bool k1 = rowok && (unsigned)(px0 + pc + 1) < WW;
                const bool k2 = rowok && (unsigned)(px0 + pc + 2) < WW;
                const bool k3 = rowok && (unsigned)(px0 + pc + 3) < WW;
                const int po = pr * PSTR + pc;
                {
                    const float* t = tabs[4 * pass + 0];
                    float* d = &phi_s[0][po];
                    d[0] = k0 ? lerp_tab(t, a0) : 0.f;
                    d[1] = k1 ? lerp_tab(t, a1) : 0.f;
                    d[2] = k2 ? lerp_tab(t, a2) : 0.f;
                    d[3] = k3 ? lerp_tab(t, a3) : 0.f;
                }
                {
                    const float* t = tabs[4 * pass + 1];
                    float* d = &phi_s[1][po];
                    d[0] = k0 ? lerp_tab(t, b0) : 0.f;
                    d[1] = k1 ? lerp_tab(t, b1) : 0.f;
                    d[2] = k2 ? lerp_tab(t, b2) : 0.f;
                    d[3] = k3 ? lerp_tab(t, b3) : 0.f;
                }
                {
                    const float* t = tabs[4 * pass + 2];
                    float* d = &phi_s[2][po];
                    d[0] = k0 ? lerp_tab(t, e0) : 0.f;
                    d[1] = k1 ? lerp_tab(t, e1) : 0.f;
                    d[2] = k2 ? lerp_tab(t, e2) : 0.f;
                    d[3] = k3 ? lerp_tab(t, e3) : 0.f;
                }
                {
                    const float* t = tabs[4 * pass + 3];
                    float* d = &phi_s[3][po];
                    d[0] = k0 ? lerp_tab(t, d0) : 0.f;
                    d[1] = k1 ? lerp_tab(t, d1) : 0.f;
                    d[2] = k2 ? lerp_tab(t, d2) : 0.f;
                    d[3] = k3 ? lerp_tab(t, d3) : 0.f;
                }
            }
        }
        __syncthreads();

        // ---- conv2 accumulate 4 channels, spatially-flipped weights ----
        const int co = oy * PSTR + ox0;
        #pragma unroll
        for (int dy = 0; dy < 7; ++dy) {
            const float* rA = &phi_s[0][co + dy * PSTR];
            const float* rB = &phi_s[1][co + dy * PSTR];
            const float* rC = &phi_s[2][co + dy * PSTR];
            const float* rD = &phi_s[3][co + dy * PSTR];
            float sa[10], sb[10], sc[10], sd[10];
            #pragma unroll
            for (int j = 0; j < 10; ++j) sa[j] = rA[j];
            #pragma unroll
            for (int j = 0; j < 10; ++j) sb[j] = rB[j];
            #pragma unroll
            for (int j = 0; j < 10; ++j) sc[j] = rC[j];
            #pragma unroll
            for (int j = 0; j < 10; ++j) sd[j] = rD[j];
            #pragma unroll
            for (int dx = 0; dx < 7; ++dx) {
                const float fa = wA[(6 - dy) * 7 + (6 - dx)];
                const float fb = wB[(6 - dy) * 7 + (6 - dx)];
                const float fc = wC[(6 - dy) * 7 + (6 - dx)];
                const float fd = wD[(6 - dy) * 7 + (6 - dx)];
                o0 = fmaf(sa[dx],     fa, o0);
                o1 = fmaf(sa[dx + 1], fa, o1);
                o2 = fmaf(sa[dx + 2], fa, o2);
                o3 = fmaf(sa[dx + 3], fa, o3);
                o0 = fmaf(sb[dx],     fb, o0);
                o1 = fmaf(sb[dx + 1], fb, o1);
                o2 = fmaf(sb[dx + 2], fb, o2);
                o3 = fmaf(sb[dx + 3], fb, o3);
                o0 = fmaf(sc[dx],     fc, o0);
                o1 = fmaf(sc[dx + 1], fc, o1);
                o2 = fmaf(sc[dx + 2], fc, o2);
                o3 = fmaf(sc[dx + 3], fc, o3);
                o0 = fmaf(sd[dx],     fd, o0);
                o1 = fmaf(sd[dx + 1], fd, o1);
                o2 = fmaf(sd[dx + 2], fd, o2);
                o3 = fmaf(sd[dx + 3], fd, o3);
            }
        }
        if (pass == 0) __syncthreads();   // protect phi_s before next pass
    }

    const int gy = by * OT + oy, gx = bx * OT + ox0;
    float4 v4 = make_float4(o0, o1, o2, o3);
    *reinterpret_cast<float4*>(part + (size_t)g * NPIX + b * (HH * WW)
                               + gy * WW + gx) = v4;
}

__global__ __launch_bounds__(256)
void combine_kernel(const float* __restrict__ u,
                    const float* __restrict__ f,
                    const float* __restrict__ lam,
                    const float* __restrict__ part,
                    float* __restrict__ out)
{
    int i = blockIdx.x * 256 + threadIdx.x;  // 512 blocks -> NPIX
    float d = 0.f;
    #pragma unroll
    for (int g = 0; g < NG; ++g) d += part[g * NPIX + i];
    float lv = lam[0];
    float uv = u[i];
    float fv = f[i];
    out[i] = uv - d - lv * (uv - fv);
}

extern "C" void kernel_launch(void* const* d_in, const int* in_sizes, int n_in,
                              void* d_out, int out_size, void* d_ws, size_t ws_size,
                              hipStream_t stream) {
    const float* u    = (const float*)d_in[0];
    const float* f    = (const float*)d_in[1];
    const float* filt = (const float*)d_in[2];
    const float* rbfw = (const float*)d_in[3];
    const float* lam  = (const float*)d_in[4];
    float* out = (float*)d_out;
    float* part = (float*)d_ws;   // 6 * 131072 f32 partial sums (3 MB)

    tnrd_main<<<dim3(8, 8, 2 * NG), 256, 0, stream>>>(u, filt, rbfw, part);
    combine_kernel<<<512, 256, 0, stream>>>(u, f, lam, part, out);
}